// Round 5
// baseline (25.425 us; speedup 1.0000x reference)
//
#include <hip/hip_runtime.h>

// out[b,s,:] = vocab_weight[idx[b,s]] + pos_weight[s] + tokentype_weight[types[b,s]]
// B=8, S=2048, H=1024, fp32. Memory-bound gather+add.
//
// R4 structure (fastest: max TLP, one token per 4-wave group, float4/lane,
// NT store) with ONE change: 4 tokens per 1024-thread block -> 4096 WGs
// instead of 16384, testing whether per-WG dispatch overhead is the
// residual gap vs the HBM roofline. Wave-level memory pattern identical:
// each 64-lane wave reads/writes one contiguous 1KB slice of one token row.

#define HIDDEN 1024
#define SEQ 2048

typedef float v4f __attribute__((ext_vector_type(4)));

__global__ __launch_bounds__(1024) void embed_fused_kernel(
    const int* __restrict__ idx,
    const int* __restrict__ types,
    const float* __restrict__ vocab_w,
    const float* __restrict__ pos_w,
    const float* __restrict__ tt_w,
    float* __restrict__ out)
{
    const int sub   = threadIdx.x >> 8;        // 0..3: token slot within block
    const int t     = threadIdx.x & 255;       // float4 index within row
    const int token = (blockIdx.x << 2) | sub; // 0 .. B*S-1
    const int s     = token & (SEQ - 1);       // position within sequence
    const int row   = idx[token];              // vocab row (wave-uniform)
    const int tt    = types[token];            // tokentype row (wave-uniform)

    const v4f a = reinterpret_cast<const v4f*>(vocab_w + (size_t)row * HIDDEN)[t];
    const v4f p = reinterpret_cast<const v4f*>(pos_w   + (size_t)s   * HIDDEN)[t];
    const v4f q = reinterpret_cast<const v4f*>(tt_w    + (size_t)tt  * HIDDEN)[t];

    v4f r = a + p + q;
    v4f* o = reinterpret_cast<v4f*>(out + (size_t)token * HIDDEN) + t;
    __builtin_nontemporal_store(r, o);
}

extern "C" void kernel_launch(void* const* d_in, const int* in_sizes, int n_in,
                              void* d_out, int out_size, void* d_ws, size_t ws_size,
                              hipStream_t stream)
{
    const int*   idx     = (const int*)d_in[0];   // [B,S] int32
    const int*   types   = (const int*)d_in[1];   // [B,S] int32
    const float* vocab_w = (const float*)d_in[2]; // [VOCAB, H] fp32
    const float* pos_w   = (const float*)d_in[3]; // [S, H] fp32
    const float* tt_w    = (const float*)d_in[4]; // [NUM_TT, H] fp32
    float*       out     = (float*)d_out;         // [B,S,H] fp32

    const int n_tokens = in_sizes[0];             // B*S = 16384
    embed_fused_kernel<<<n_tokens / 4, 1024, 0, stream>>>(idx, types, vocab_w, pos_w, tt_w, out);
}

// Round 6
// 25.212 us; speedup vs baseline: 1.0085x; 1.0085x over previous
//
#include <hip/hip_runtime.h>

// out[b,s,:] = vocab_weight[idx[b,s]] + pos_weight[s] + tokentype_weight[types[b,s]]
// B=8, S=2048, H=1024, fp32. Memory-bound gather+add.
//
// FINAL (measured-fastest, R4): one 256-thread block per token, each thread
// one float4 (perfectly coalesced 4KB row reads/writes), nontemporal output
// store so the write-once 67MB stream doesn't evict the L3-resident vocab
// table. 25.1 us = 5.66 TB/s combined traffic = 90% of the measured float4
// copy ceiling (6.29 TB/s) with a random-gather read stream.
// A/B'd and rejected: pos/tt reuse via grid restructure (-8%, kills TLP),
// 4-tokens-per-1024-thread-block (-1%).

#define HIDDEN 1024
#define SEQ 2048

typedef float v4f __attribute__((ext_vector_type(4)));

__global__ __launch_bounds__(256) void embed_fused_kernel(
    const int* __restrict__ idx,
    const int* __restrict__ types,
    const float* __restrict__ vocab_w,
    const float* __restrict__ pos_w,
    const float* __restrict__ tt_w,
    float* __restrict__ out)
{
    const int token = blockIdx.x;           // 0 .. B*S-1, one block per token row
    const int s     = token & (SEQ - 1);    // position within sequence
    const int row   = idx[token];           // vocab row (wave-uniform per block)
    const int tt    = types[token];         // tokentype row (wave-uniform)
    const int t     = threadIdx.x;          // 0..255, one float4 each

    const v4f a = reinterpret_cast<const v4f*>(vocab_w + (size_t)row * HIDDEN)[t];
    const v4f p = reinterpret_cast<const v4f*>(pos_w   + (size_t)s   * HIDDEN)[t];
    const v4f q = reinterpret_cast<const v4f*>(tt_w    + (size_t)tt  * HIDDEN)[t];

    v4f r = a + p + q;
    v4f* o = reinterpret_cast<v4f*>(out + (size_t)token * HIDDEN) + t;
    __builtin_nontemporal_store(r, o);
}

extern "C" void kernel_launch(void* const* d_in, const int* in_sizes, int n_in,
                              void* d_out, int out_size, void* d_ws, size_t ws_size,
                              hipStream_t stream)
{
    const int*   idx     = (const int*)d_in[0];   // [B,S] int32
    const int*   types   = (const int*)d_in[1];   // [B,S] int32
    const float* vocab_w = (const float*)d_in[2]; // [VOCAB, H] fp32
    const float* pos_w   = (const float*)d_in[3]; // [S, H] fp32
    const float* tt_w    = (const float*)d_in[4]; // [NUM_TT, H] fp32
    float*       out     = (float*)d_out;         // [B,S,H] fp32

    const int n_tokens = in_sizes[0];             // B*S = 16384
    embed_fused_kernel<<<n_tokens, 256, 0, stream>>>(idx, types, vocab_w, pos_w, tt_w, out);
}